// Round 3
// baseline (311.481 us; speedup 1.0000x reference)
//
#include <hip/hip_runtime.h>

// v: [E, 64, 3] f32, k: [E, 8, 16] f32, q: [N, 8, 16] f32, dst: [E] i32
// out: [N, 64, 3] f32.  H=8 heads, T=16, 8 value channels/head, D=3.
#define HH 8
#define CAPL 128     // per-wave LDS edge cache (Poisson(16): P(deg>128) ~ 1e-58)
#define BSTRIDE 256  // bucket stride = max supported degree

static constexpr float SCALE = 0.08838834764831843f;  // 1/sqrt(8*16)

struct f3 {
  float x, y, z;
};  // align(4): stride-12 loads -> global_load_dwordx3

__device__ __forceinline__ float dot16q(const float* kp, float4 q0, float4 q1,
                                        float4 q2, float4 q3) {
  const float4* k4 = (const float4*)kp;
  float4 a = k4[0], b = k4[1], c = k4[2], d = k4[3];
  float acc = a.x * q0.x + a.y * q0.y + a.z * q0.z + a.w * q0.w;
  acc += b.x * q1.x + b.y * q1.y + b.z * q1.z + b.w * q1.w;
  acc += c.x * q2.x + c.y * q2.y + c.z * q2.z + c.w * q2.w;
  acc += d.x * q3.x + d.y * q3.y + d.z * q3.z + d.w * q3.w;
  return acc;
}

// Pass 1: bucket-append edge ids per destination node (no CSR scan).
__global__ __launch_bounds__(256) void fill_kernel(const int* __restrict__ dst,
                                                   int* __restrict__ cursor,
                                                   int* __restrict__ eid,
                                                   int E) {
  int e = blockIdx.x * blockDim.x + threadIdx.x;
  if (e >= E) return;
  int d = dst[e];
  int pos = atomicAdd(&cursor[d], 1);
  if (pos < BSTRIDE) eid[(size_t)d * BSTRIDE + pos] = e;
}

// Pass 2: one wave per node, fused logits -> softmax -> weighted sum.
// All LDS wave-private, no __syncthreads.
__global__ __launch_bounds__(256) void node_kernel(
    const float* __restrict__ v, const float* __restrict__ k,
    const float* __restrict__ q, const int* __restrict__ cursor,
    const int* __restrict__ eid, float* __restrict__ out, int N) {
  __shared__ int eidL[4][CAPL];
  __shared__ float wL[4][CAPL * HH];  // logits, then exp values
  __shared__ float ovfL[4][HH];       // overflow-edge weights (never used)

  int tid = threadIdx.x;
  int wave = tid >> 6;
  int lane = tid & 63;
  int node = blockIdx.x * 4 + wave;
  if (node >= N) return;

  int deg = cursor[node];
  int nl = min(deg, CAPL);
  int nb = min(deg, BSTRIDE);
  const int* bucket = eid + (size_t)node * BSTRIDE;
  const char* vB = (const char*)v;
  const char* kB = (const char*)k;
  uint32_t vlane = (uint32_t)(lane * 12);

  // Cache edge ids in LDS (wave-private).
  for (int i = lane; i < nl; i += 64) eidL[wave][i] = bucket[i];

  int h = lane & 7;   // head owned in phases 1-2
  int j = lane >> 3;  // edge-slot residue in phases 1-2

  // Prefetch first 4 v rows: addresses depend only on eid, not on softmax,
  // so this ~700cy miss hides under phases 1-2.
  f3 p0 = {0, 0, 0}, p1 = {0, 0, 0}, p2 = {0, 0, 0}, p3 = {0, 0, 0};
  if (nl > 0) {
    int i1 = min(1, nl - 1), i2 = min(2, nl - 1), i3 = min(3, nl - 1);
    int e0 = eidL[wave][0], e1 = eidL[wave][i1];
    int e2 = eidL[wave][i2], e3 = eidL[wave][i3];
    p0 = *(const f3*)(vB + (uint32_t)e0 * 768u + vlane);
    p1 = *(const f3*)(vB + (uint32_t)e1 * 768u + vlane);
    p2 = *(const f3*)(vB + (uint32_t)e2 * 768u + vlane);
    p3 = *(const f3*)(vB + (uint32_t)e3 * 768u + vlane);
  }

  // q row for head h -> registers (8 lanes share each 64B chunk).
  const float4* qq = (const float4*)(q + (size_t)node * 128 + h * 16);
  float4 q0 = qq[0], q1 = qq[1], q2 = qq[2], q3 = qq[3];

  // Phase 1: logits into LDS + per-(residue,head) running max. Unroll x2 so
  // both edges' 4 k-loads are in flight together.
  float m = -1e30f;
  uint32_t kh = (uint32_t)(h * 64);
  {
    int i = j;
    for (; i + 8 < nl; i += 16) {
      int e0 = eidL[wave][i];
      int e1 = eidL[wave][i + 8];
      float lg0 =
          dot16q((const float*)(kB + (uint32_t)e0 * 512u + kh), q0, q1, q2, q3) *
          SCALE;
      float lg1 =
          dot16q((const float*)(kB + (uint32_t)e1 * 512u + kh), q0, q1, q2, q3) *
          SCALE;
      wL[wave][i * 8 + h] = lg0;
      wL[wave][(i + 8) * 8 + h] = lg1;
      m = fmaxf(m, fmaxf(lg0, lg1));
    }
    for (; i < nl; i += 8) {
      int e = eidL[wave][i];
      float lg =
          dot16q((const float*)(kB + (uint32_t)e * 512u + kh), q0, q1, q2, q3) *
          SCALE;
      wL[wave][i * 8 + h] = lg;
      m = fmaxf(m, lg);
    }
  }
  for (int i = CAPL + j; i < nb; i += 8) {  // overflow (never in practice)
    int e = bucket[i];
    float lg = dot16q(k + (size_t)e * 128 + h * 16, q0, q1, q2, q3) * SCALE;
    m = fmaxf(m, lg);
  }
  m = fmaxf(m, __shfl_xor(m, 8, 64));
  m = fmaxf(m, __shfl_xor(m, 16, 64));
  m = fmaxf(m, __shfl_xor(m, 32, 64));

  // Phase 2: exp in place + denom (LDS-only).
  float s = 0.f;
  for (int i = j; i < nl; i += 8) {
    float ex = __expf(wL[wave][i * 8 + h] - m);
    wL[wave][i * 8 + h] = ex;
    s += ex;
  }
  for (int i = CAPL + j; i < nb; i += 8) {  // overflow
    int e = bucket[i];
    float lg = dot16q(k + (size_t)e * 128 + h * 16, q0, q1, q2, q3) * SCALE;
    s += __expf(lg - m);
  }
  s += __shfl_xor(s, 8, 64);
  s += __shfl_xor(s, 16, 64);
  s += __shfl_xor(s, 32, 64);
  float inv = (s > 0.f) ? 1.0f / s : 0.f;  // deg==0 -> zeros, not NaN

  // Phase 3: channel accumulation. Lane owns channel `lane`, head hc=lane>>3.
  // Unroll x4: 4 independent dwordx3 loads in flight per batch.
  int hc = lane >> 3;
  float minv = __shfl(inv, hc, 64);  // lane hc holds head hc's denom
  float a0 = 0.f, a1 = 0.f, a2 = 0.f;

  if (nl > 0) {  // batch 0 from prefetch (w-guards zero the clamped dups)
    float w0 = wL[wave][0 * 8 + hc];
    float w1 = (1 < nl) ? wL[wave][1 * 8 + hc] : 0.f;
    float w2 = (2 < nl) ? wL[wave][2 * 8 + hc] : 0.f;
    float w3 = (3 < nl) ? wL[wave][3 * 8 + hc] : 0.f;
    a0 = w0 * p0.x + w1 * p1.x + w2 * p2.x + w3 * p3.x;
    a1 = w0 * p0.y + w1 * p1.y + w2 * p2.y + w3 * p3.y;
    a2 = w0 * p0.z + w1 * p1.z + w2 * p2.z + w3 * p3.z;
  }
  int i = 4;
  for (; i + 4 <= nl; i += 4) {
    int e0 = eidL[wave][i + 0];
    int e1 = eidL[wave][i + 1];
    int e2 = eidL[wave][i + 2];
    int e3 = eidL[wave][i + 3];
    float w0 = wL[wave][(i + 0) * 8 + hc];
    float w1 = wL[wave][(i + 1) * 8 + hc];
    float w2 = wL[wave][(i + 2) * 8 + hc];
    float w3 = wL[wave][(i + 3) * 8 + hc];
    f3 v0 = *(const f3*)(vB + (uint32_t)e0 * 768u + vlane);
    f3 v1 = *(const f3*)(vB + (uint32_t)e1 * 768u + vlane);
    f3 v2 = *(const f3*)(vB + (uint32_t)e2 * 768u + vlane);
    f3 v3 = *(const f3*)(vB + (uint32_t)e3 * 768u + vlane);
    a0 += w0 * v0.x + w1 * v1.x + w2 * v2.x + w3 * v3.x;
    a1 += w0 * v0.y + w1 * v1.y + w2 * v2.y + w3 * v3.y;
    a2 += w0 * v0.z + w1 * v1.z + w2 * v2.z + w3 * v3.z;
  }
  for (; i < nl; ++i) {
    int e = eidL[wave][i];
    float w = wL[wave][i * 8 + hc];
    f3 vv = *(const f3*)(vB + (uint32_t)e * 768u + vlane);
    a0 += w * vv.x;
    a1 += w * vv.y;
    a2 += w * vv.z;
  }
  for (int ii = CAPL; ii < nb; ++ii) {  // overflow (never in practice)
    int e = bucket[ii];
    if (lane < 8) {  // lane<8 has h==lane, correct m for that head
      float lg = dot16q(k + (size_t)e * 128 + lane * 16, q0, q1, q2, q3) * SCALE;
      ovfL[wave][lane] = __expf(lg - m);
    }
    float w = ovfL[wave][hc];  // same-wave LDS RAW: lgkmcnt ordering
    f3 vv = *(const f3*)(vB + (uint32_t)e * 768u + vlane);
    a0 += w * vv.x;
    a1 += w * vv.y;
    a2 += w * vv.z;
  }
  a0 *= minv;
  a1 *= minv;
  a2 *= minv;

  f3* op = (f3*)((char*)out + (uint32_t)node * 768u + vlane);
  op->x = a0;
  op->y = a1;
  op->z = a2;
}

extern "C" void kernel_launch(void* const* d_in, const int* in_sizes, int n_in,
                              void* d_out, int out_size, void* d_ws,
                              size_t ws_size, hipStream_t stream) {
  const float* v = (const float*)d_in[0];
  const float* k = (const float*)d_in[1];
  const float* q = (const float*)d_in[2];
  const int* dst = (const int*)d_in[3];
  float* out = (float*)d_out;

  const int E = in_sizes[3];              // 800000
  const int N = in_sizes[2] / (HH * 16);  // 50000

  char* ws = (char*)d_ws;
  int* cursor = (int*)ws;  // N ints
  int* eid = (int*)(ws + (((size_t)N * 4 + 255) & ~(size_t)255));  // N*BSTRIDE

  hipMemsetAsync(cursor, 0, (size_t)N * sizeof(int), stream);
  fill_kernel<<<(E + 255) / 256, 256, 0, stream>>>(dst, cursor, eid, E);
  node_kernel<<<(N + 3) / 4, 256, 0, stream>>>(v, k, q, cursor, eid, out, N);
}